// Round 1
// baseline (142.645 us; speedup 1.0000x reference)
//
#include <hip/hip_runtime.h>

#define SEQ 1024
#define HEADS 16
#define HD 64
#define EMB 1024

typedef short bf16x8 __attribute__((ext_vector_type(8)));
typedef float f32x4 __attribute__((ext_vector_type(4)));

// float -> bf16 bits, round-to-nearest-even (no NaN inputs in this problem)
static __device__ __forceinline__ unsigned short f2bf(float f) {
  unsigned u = __builtin_bit_cast(unsigned, f);
  u += 0x7FFFu + ((u >> 16) & 1u);
  return (unsigned short)(u >> 16);
}

static __device__ __forceinline__ void gload_lds16(const void* g, void* l) {
  __builtin_amdgcn_global_load_lds((const __attribute__((address_space(1))) unsigned int*)g,
                                   (__attribute__((address_space(3))) unsigned int*)l,
                                   16, 0, 0);
}

// ---------------- mask bitpack: [N,1,S,S] int32 -> [N,S,S/64] u64 ----------------
__global__ __launch_bounds__(256) void k_maskpack(const int* __restrict__ mask,
                                                  unsigned long long* __restrict__ mb) {
  const unsigned gw = (blockIdx.x * 256u + threadIdx.x) >> 6;
  const unsigned lane = threadIdx.x & 63u;
  const int v = mask[(size_t)gw * 64u + lane];
  const unsigned long long bits = __ballot(v != 0);
  if (lane == 0) mb[gw] = bits;
}

// ---------------- Wo f32 -> bf16 ----------------
__global__ __launch_bounds__(256) void k_cvtwo(const float* __restrict__ Wo,
                                               unsigned short* __restrict__ wob) {
  const unsigned i = blockIdx.x * 256u + threadIdx.x;
  const float4 f = ((const float4*)Wo)[i];
  ushort4 o;
  o.x = f2bf(f.x); o.y = f2bf(f.y); o.z = f2bf(f.z); o.w = f2bf(f.w);
  ((ushort4*)wob)[i] = o;
}

// ---------------- projections: per-head 64x64, via 16x16x32 bf16 MFMA ----------------
// wave = (tensor t, n, h, 16-row block). out layout [N][H][S][D] bf16.
// 1/sqrt(EMB)=1/32 folded into Wq.
__global__ __launch_bounds__(256) void k_proj(const float* __restrict__ values,
                                              const float* __restrict__ query,
                                              const float* __restrict__ key,
                                              const float* __restrict__ Wv,
                                              const float* __restrict__ Wq,
                                              const float* __restrict__ Wk,
                                              unsigned short* __restrict__ vb,
                                              unsigned short* __restrict__ qb,
                                              unsigned short* __restrict__ kb) {
  const int lane = threadIdx.x & 63;
  const int c = lane & 15, g = lane >> 4;
  const int wid = blockIdx.x * 4 + (threadIdx.x >> 6);
  const int t = wid >> 12;          // 0..2
  const int rem = wid & 4095;
  const int n = rem >> 10;
  const int h = (rem >> 6) & 15;
  const int lb = rem & 63;          // 16-row block index

  const float* x; const float* W; unsigned short* out; float wscale;
  if (t == 0)      { x = values; W = Wv; out = vb; wscale = 1.0f; }
  else if (t == 1) { x = query;  W = Wq; out = qb; wscale = 0.03125f; }
  else             { x = key;    W = Wk; out = kb; wscale = 1.0f; }

  // A-frags: rows lb*16 + c, k = ks*32 + g*8 + j  (f32 -> bf16)
  bf16x8 a[2];
  const float* xr = x + ((size_t)n * SEQ + lb * 16 + c) * EMB + h * HD;
  #pragma unroll
  for (int ks = 0; ks < 2; ++ks) {
    const float4 f0 = *(const float4*)(xr + ks * 32 + g * 8);
    const float4 f1 = *(const float4*)(xr + ks * 32 + g * 8 + 4);
    bf16x8 v;
    v[0] = (short)f2bf(f0.x); v[1] = (short)f2bf(f0.y);
    v[2] = (short)f2bf(f0.z); v[3] = (short)f2bf(f0.w);
    v[4] = (short)f2bf(f1.x); v[5] = (short)f2bf(f1.y);
    v[6] = (short)f2bf(f1.z); v[7] = (short)f2bf(f1.w);
    a[ks] = v;
  }

  f32x4 acc[4] = {};
  #pragma unroll
  for (int cb = 0; cb < 4; ++cb) {
    #pragma unroll
    for (int ks = 0; ks < 2; ++ks) {
      // B[k][col] = W[col][k]; col = cb*16 + c, k = ks*32 + g*8 + j
      const float* wp = W + (cb * 16 + c) * HD + ks * 32 + g * 8;
      const float4 f0 = *(const float4*)wp;
      const float4 f1 = *(const float4*)(wp + 4);
      bf16x8 b;
      b[0] = (short)f2bf(f0.x * wscale); b[1] = (short)f2bf(f0.y * wscale);
      b[2] = (short)f2bf(f0.z * wscale); b[3] = (short)f2bf(f0.w * wscale);
      b[4] = (short)f2bf(f1.x * wscale); b[5] = (short)f2bf(f1.y * wscale);
      b[6] = (short)f2bf(f1.z * wscale); b[7] = (short)f2bf(f1.w * wscale);
      acc[cb] = __builtin_amdgcn_mfma_f32_16x16x32_bf16(a[ks], b, acc[cb], 0, 0, 0);
    }
  }

  // C/D: row = 4g + r, col = cb*16 + c
  unsigned short* op = out + ((size_t)(n * HEADS + h) * SEQ + lb * 16) * HD;
  #pragma unroll
  for (int cb = 0; cb < 4; ++cb)
    #pragma unroll
    for (int r = 0; r < 4; ++r)
      op[(4 * g + r) * HD + cb * 16 + c] = f2bf(acc[cb][r]);
}

// ---------------- flash attention ----------------
// block = (n, h, 64 q-rows); 4 waves x 16 q-rows. K/V tiles of 64 keys in LDS.
__global__ __launch_bounds__(256) void k_attn(const unsigned short* __restrict__ qb,
                                              const unsigned short* __restrict__ kb,
                                              const unsigned short* __restrict__ vb,
                                              const unsigned long long* __restrict__ mb,
                                              unsigned short* __restrict__ ob) {
  const int tid = threadIdx.x;
  const int w = tid >> 6, lane = tid & 63;
  const int c = lane & 15, g = lane >> 4;
  const int bid = blockIdx.x;
  const int q64 = bid & 15, h = (bid >> 4) & 15, n = bid >> 8;
  const int qlo = q64 * 64 + w * 16;

  __shared__ unsigned short Ks[64][72];      // K[key][d], +8 pad -> 2-way banks
  __shared__ unsigned short Vt[64][72];      // V^T[d][key]
  __shared__ unsigned short Pl[4][16][72];   // per-wave P tile

  const size_t nh = (size_t)(n * HEADS + h) * SEQ;
  const unsigned short* qp = qb + nh * HD;
  const unsigned short* kp = kb + nh * HD;
  const unsigned short* vp = vb + nh * HD;

  // Q A-frags (rows qlo + c)
  const bf16x8 qa0 = *(const bf16x8*)(qp + (size_t)(qlo + c) * HD + g * 8);
  const bf16x8 qa1 = *(const bf16x8*)(qp + (size_t)(qlo + c) * HD + 32 + g * 8);

  f32x4 o0 = {}, o1 = {}, o2 = {}, o3 = {};            // O[row=4g+r][db*16+c]
  float m_r[4] = {-1e30f, -1e30f, -1e30f, -1e30f};
  float l_r[4] = {0.f, 0.f, 0.f, 0.f};

  const int srow = tid >> 2;   // staging: 4 threads per key row
  const int sseg = tid & 3;    // 16-element segment

  for (int kt = 0; kt < 16; ++kt) {
    __syncthreads();
    {
      const int k0 = kt * 64;
      const unsigned short* ksrc = kp + (size_t)(k0 + srow) * HD + sseg * 16;
      const uint4 kv0 = *(const uint4*)ksrc;
      const uint4 kv1 = *(const uint4*)(ksrc + 8);
      *(uint4*)&Ks[srow][sseg * 16] = kv0;
      *(uint4*)&Ks[srow][sseg * 16 + 8] = kv1;
      const unsigned short* vsrc = vp + (size_t)(k0 + srow) * HD + sseg * 16;
      const uint4 vv0 = *(const uint4*)vsrc;
      const uint4 vv1 = *(const uint4*)(vsrc + 8);
      const unsigned short* vu0 = (const unsigned short*)&vv0;
      const unsigned short* vu1 = (const unsigned short*)&vv1;
      #pragma unroll
      for (int j = 0; j < 8; ++j) Vt[sseg * 16 + j][srow] = vu0[j];
      #pragma unroll
      for (int j = 0; j < 8; ++j) Vt[sseg * 16 + 8 + j][srow] = vu1[j];
    }
    __syncthreads();

    // S = Q K^T (already scaled via Wq): 4 key-subtiles of 16
    f32x4 s[4];
    #pragma unroll
    for (int sub = 0; sub < 4; ++sub) {
      const bf16x8 b0 = *(const bf16x8*)&Ks[sub * 16 + c][g * 8];
      const bf16x8 b1 = *(const bf16x8*)&Ks[sub * 16 + c][32 + g * 8];
      f32x4 acc = {};
      acc = __builtin_amdgcn_mfma_f32_16x16x32_bf16(qa0, b0, acc, 0, 0, 0);
      acc = __builtin_amdgcn_mfma_f32_16x16x32_bf16(qa1, b1, acc, 0, 0, 0);
      s[sub] = acc;
    }

    // online softmax per q-row (rows 4g+r); keys of this tile in bits[0..63]
    #pragma unroll
    for (int r = 0; r < 4; ++r) {
      const unsigned long long bits = mb[(size_t)(n * SEQ + qlo + 4 * g + r) * 16 + kt];
      const float NEG = -3.125e18f;  // -1e20 / sqrt(EMB)
      float v0 = ((bits >> (c)) & 1ull)      ? s[0][r] : NEG;
      float v1 = ((bits >> (16 + c)) & 1ull) ? s[1][r] : NEG;
      float v2 = ((bits >> (32 + c)) & 1ull) ? s[2][r] : NEG;
      float v3 = ((bits >> (48 + c)) & 1ull) ? s[3][r] : NEG;
      float tm = fmaxf(fmaxf(v0, v1), fmaxf(v2, v3));
      tm = fmaxf(tm, __shfl_xor(tm, 1));
      tm = fmaxf(tm, __shfl_xor(tm, 2));
      tm = fmaxf(tm, __shfl_xor(tm, 4));
      tm = fmaxf(tm, __shfl_xor(tm, 8));
      const float mnew = fmaxf(m_r[r], tm);
      const float sc = __expf(m_r[r] - mnew);
      const float p0 = __expf(v0 - mnew);
      const float p1 = __expf(v1 - mnew);
      const float p2 = __expf(v2 - mnew);
      const float p3 = __expf(v3 - mnew);
      float rs = p0 + p1 + p2 + p3;
      rs += __shfl_xor(rs, 1);
      rs += __shfl_xor(rs, 2);
      rs += __shfl_xor(rs, 4);
      rs += __shfl_xor(rs, 8);
      l_r[r] = l_r[r] * sc + rs;
      m_r[r] = mnew;
      o0[r] *= sc; o1[r] *= sc; o2[r] *= sc; o3[r] *= sc;
      Pl[w][4 * g + r][c]      = f2bf(p0);
      Pl[w][4 * g + r][16 + c] = f2bf(p1);
      Pl[w][4 * g + r][32 + c] = f2bf(p2);
      Pl[w][4 * g + r][48 + c] = f2bf(p3);
    }

    // O += P V  (A = P from LDS, B = V^T rows)
    #pragma unroll
    for (int ks = 0; ks < 2; ++ks) {
      const bf16x8 pa = *(const bf16x8*)&Pl[w][c][ks * 32 + g * 8];
      const bf16x8 bv0 = *(const bf16x8*)&Vt[c][ks * 32 + g * 8];
      const bf16x8 bv1 = *(const bf16x8*)&Vt[16 + c][ks * 32 + g * 8];
      const bf16x8 bv2 = *(const bf16x8*)&Vt[32 + c][ks * 32 + g * 8];
      const bf16x8 bv3 = *(const bf16x8*)&Vt[48 + c][ks * 32 + g * 8];
      o0 = __builtin_amdgcn_mfma_f32_16x16x32_bf16(pa, bv0, o0, 0, 0, 0);
      o1 = __builtin_amdgcn_mfma_f32_16x16x32_bf16(pa, bv1, o1, 0, 0, 0);
      o2 = __builtin_amdgcn_mfma_f32_16x16x32_bf16(pa, bv2, o2, 0, 0, 0);
      o3 = __builtin_amdgcn_mfma_f32_16x16x32_bf16(pa, bv3, o3, 0, 0, 0);
    }
  }

  // normalize and store to [N][S][E] bf16
  #pragma unroll
  for (int r = 0; r < 4; ++r) {
    const float inv = 1.0f / l_r[r];
    unsigned short* orow = ob + ((size_t)(n * SEQ) + qlo + 4 * g + r) * EMB + h * HD;
    orow[c]      = f2bf(o0[r] * inv);
    orow[16 + c] = f2bf(o1[r] * inv);
    orow[32 + c] = f2bf(o2[r] * inv);
    orow[48 + c] = f2bf(o3[r] * inv);
  }
}

// ---------------- out-proj GEMM: C[4096,1024] = A[4096,1024] * B[1024,1024]^T + bo ----------------
// m97-style: 128x128 tile, BK=64, global_load_lds(16B), 4 waves 2x2.
__global__ __launch_bounds__(256) void k_gemm(const unsigned short* __restrict__ A,
                                              const unsigned short* __restrict__ B,
                                              const float* __restrict__ bo,
                                              float* __restrict__ C) {
  const int tid = threadIdx.x;
  const int w = tid >> 6, lane = tid & 63;
  const int c = lane & 15, g = lane >> 4;
  const int bm = blockIdx.x & 31, bn = blockIdx.x >> 5;
  const int m0 = bm * 128, n0 = bn * 128;
  const int wr = w >> 1, wc = w & 1;

  __shared__ unsigned short As[128][64];
  __shared__ unsigned short Bs[128][64];

  f32x4 acc[4][4] = {};

  for (int kt = 0; kt < 16; ++kt) {
    __syncthreads();
    #pragma unroll
    for (int rd = 0; rd < 4; ++rd) {
      const int off = (rd * 4 + w) * 1024 + lane * 16;  // byte offset in 16KB tile
      const int row = off >> 7;
      const int colb = off & 127;
      gload_lds16((const char*)A + ((size_t)(m0 + row) * 1024 + kt * 64) * 2 + colb,
                  (char*)&As[0][0] + off);
      gload_lds16((const char*)B + ((size_t)(n0 + row) * 1024 + kt * 64) * 2 + colb,
                  (char*)&Bs[0][0] + off);
    }
    __syncthreads();
    #pragma unroll
    for (int ks = 0; ks < 2; ++ks) {
      bf16x8 af[4], bf_[4];
      #pragma unroll
      for (int i = 0; i < 4; ++i)
        af[i] = *(const bf16x8*)&As[wr * 64 + i * 16 + c][ks * 32 + g * 8];
      #pragma unroll
      for (int i = 0; i < 4; ++i)
        bf_[i] = *(const bf16x8*)&Bs[wc * 64 + i * 16 + c][ks * 32 + g * 8];
      #pragma unroll
      for (int i = 0; i < 4; ++i)
        #pragma unroll
        for (int j = 0; j < 4; ++j)
          acc[i][j] = __builtin_amdgcn_mfma_f32_16x16x32_bf16(af[i], bf_[j], acc[i][j], 0, 0, 0);
    }
  }

  #pragma unroll
  for (int j = 0; j < 4; ++j) {
    const int col = n0 + wc * 64 + j * 16 + c;
    const float bv = bo[col];
    #pragma unroll
    for (int i = 0; i < 4; ++i) {
      const int rowb = m0 + wr * 64 + i * 16 + 4 * g;
      #pragma unroll
      for (int r = 0; r < 4; ++r)
        C[(size_t)(rowb + r) * 1024 + col] = acc[i][j][r] + bv;
    }
  }
}

extern "C" void kernel_launch(void* const* d_in, const int* in_sizes, int n_in,
                              void* d_out, int out_size, void* d_ws, size_t ws_size,
                              hipStream_t stream) {
  const float* values = (const float*)d_in[0];
  const float* query  = (const float*)d_in[1];
  const float* key    = (const float*)d_in[2];
  const int*   mask   = (const int*)d_in[3];
  const float* Wv     = (const float*)d_in[4];
  const float* Wk     = (const float*)d_in[5];
  const float* Wq     = (const float*)d_in[6];
  const float* Wo     = (const float*)d_in[7];
  const float* bo     = (const float*)d_in[8];
  float* out = (float*)d_out;

  char* ws = (char*)d_ws;
  unsigned short* qb = (unsigned short*)(ws);                            // 8MB  [N][H][S][D]
  unsigned short* kb = (unsigned short*)(ws + (size_t)8 * 1024 * 1024);  // 8MB
  unsigned short* vb = (unsigned short*)(ws + (size_t)16 * 1024 * 1024); // 8MB
  unsigned short* ob = (unsigned short*)(ws + (size_t)24 * 1024 * 1024); // 8MB  [N][S][E]
  unsigned long long* mb = (unsigned long long*)(ws + (size_t)32 * 1024 * 1024); // 512KB
  unsigned short* wob = (unsigned short*)(ws + (size_t)33 * 1024 * 1024);        // 2MB

  k_maskpack<<<16384, 256, 0, stream>>>(mask, mb);
  k_cvtwo<<<1024, 256, 0, stream>>>(Wo, wob);
  k_proj<<<3072, 256, 0, stream>>>(values, query, key, Wv, Wq, Wk, vb, qb, kb);
  k_attn<<<1024, 256, 0, stream>>>(qb, kb, vb, mb, ob);
  k_gemm<<<256, 256, 0, stream>>>(ob, wob, bo, out);
}

// Round 2
// 110.498 us; speedup vs baseline: 1.2909x; 1.2909x over previous
//
#include <hip/hip_runtime.h>

#define SEQ 1024
#define HEADS 16
#define HD 64
#define EMB 1024

typedef short bf16x8 __attribute__((ext_vector_type(8)));
typedef float f32x4 __attribute__((ext_vector_type(4)));

// float -> bf16 bits, round-to-nearest-even
static __device__ __forceinline__ unsigned short f2bf(float f) {
  unsigned u = __builtin_bit_cast(unsigned, f);
  u += 0x7FFFu + ((u >> 16) & 1u);
  return (unsigned short)(u >> 16);
}

static __device__ __forceinline__ void gload_lds16(const void* g, void* l) {
  __builtin_amdgcn_global_load_lds((const __attribute__((address_space(1))) unsigned int*)g,
                                   (__attribute__((address_space(3))) unsigned int*)l,
                                   16, 0, 0);
}

// ---------------- mask bitpack: [N,1,S,S] int32 -> [N,S,S/64] u64 ----------------
__global__ __launch_bounds__(256) void k_maskpack(const int* __restrict__ mask,
                                                  unsigned long long* __restrict__ mb) {
  const unsigned gw = (blockIdx.x * 256u + threadIdx.x) >> 6;
  const unsigned lane = threadIdx.x & 63u;
  const int v = mask[(size_t)gw * 64u + lane];
  const unsigned long long bits = __ballot(v != 0);
  if (lane == 0) mb[gw] = bits;
}

// ---------------- Wo f32 -> bf16, k-dim permuted: wob[e][blk*64+4c+sub] = Wo[e][blk*64+sub*16+c] ----
__global__ __launch_bounds__(256) void k_cvtwo(const float* __restrict__ Wo,
                                               unsigned short* __restrict__ wob) {
  const unsigned gid = blockIdx.x * 256u + threadIdx.x;
  const unsigned e = gid >> 8, rem = gid & 255u;
  const unsigned blk = rem >> 4, cc = rem & 15u;
  const float* src = Wo + (size_t)e * 1024 + blk * 64 + cc;
  ushort4 o;
  o.x = f2bf(src[0]);
  o.y = f2bf(src[16]);
  o.z = f2bf(src[32]);
  o.w = f2bf(src[48]);
  ((ushort4*)wob)[gid] = o;
}

// ---------------- projections -> [N][H][S][Dpi] bf16, pi(d)=4*(d&15)+(d>>4) ----------------
__global__ __launch_bounds__(256) void k_proj(const float* __restrict__ values,
                                              const float* __restrict__ query,
                                              const float* __restrict__ key,
                                              const float* __restrict__ Wv,
                                              const float* __restrict__ Wq,
                                              const float* __restrict__ Wk,
                                              unsigned short* __restrict__ vb,
                                              unsigned short* __restrict__ qb,
                                              unsigned short* __restrict__ kb) {
  const int lane = threadIdx.x & 63;
  const int c = lane & 15, g = lane >> 4;
  const int wid = blockIdx.x * 4 + (threadIdx.x >> 6);
  const int t = wid >> 12;          // 0..2
  const int rem = wid & 4095;
  const int n = rem >> 10;
  const int h = (rem >> 6) & 15;
  const int lb = rem & 63;          // 16-row block index

  const float* x; const float* W; unsigned short* out; float wscale;
  if (t == 0)      { x = values; W = Wv; out = vb; wscale = 1.0f; }
  else if (t == 1) { x = query;  W = Wq; out = qb; wscale = 0.03125f; }
  else             { x = key;    W = Wk; out = kb; wscale = 1.0f; }

  bf16x8 a[2];
  const float* xr = x + ((size_t)n * SEQ + lb * 16 + c) * EMB + h * HD;
  #pragma unroll
  for (int ks = 0; ks < 2; ++ks) {
    const float4 f0 = *(const float4*)(xr + ks * 32 + g * 8);
    const float4 f1 = *(const float4*)(xr + ks * 32 + g * 8 + 4);
    bf16x8 v;
    v[0] = (short)f2bf(f0.x); v[1] = (short)f2bf(f0.y);
    v[2] = (short)f2bf(f0.z); v[3] = (short)f2bf(f0.w);
    v[4] = (short)f2bf(f1.x); v[5] = (short)f2bf(f1.y);
    v[6] = (short)f2bf(f1.z); v[7] = (short)f2bf(f1.w);
    a[ks] = v;
  }

  f32x4 acc[4] = {};
  #pragma unroll
  for (int cb = 0; cb < 4; ++cb) {
    #pragma unroll
    for (int ks = 0; ks < 2; ++ks) {
      const float* wp = W + (cb * 16 + c) * HD + ks * 32 + g * 8;
      const float4 f0 = *(const float4*)wp;
      const float4 f1 = *(const float4*)(wp + 4);
      bf16x8 b;
      b[0] = (short)f2bf(f0.x * wscale); b[1] = (short)f2bf(f0.y * wscale);
      b[2] = (short)f2bf(f0.z * wscale); b[3] = (short)f2bf(f0.w * wscale);
      b[4] = (short)f2bf(f1.x * wscale); b[5] = (short)f2bf(f1.y * wscale);
      b[6] = (short)f2bf(f1.z * wscale); b[7] = (short)f2bf(f1.w * wscale);
      acc[cb] = __builtin_amdgcn_mfma_f32_16x16x32_bf16(a[ks], b, acc[cb], 0, 0, 0);
    }
  }

  // acc[cb][r] = out[row=lb*16+4g+r][e = cb*16+c]; store at dpos=4c+cb -> ushort4
  unsigned short* op = out + ((size_t)(n * HEADS + h) * SEQ + lb * 16) * HD;
  #pragma unroll
  for (int r = 0; r < 4; ++r) {
    ushort4 pk;
    pk.x = f2bf(acc[0][r]); pk.y = f2bf(acc[1][r]);
    pk.z = f2bf(acc[2][r]); pk.w = f2bf(acc[3][r]);
    *(ushort4*)(op + (4 * g + r) * HD + 4 * c) = pk;
  }
}

// ---------------- flash attention, max-free softmax ----------------
// block = (n, h, 128 q-rows); 4 waves x 32 q-rows (2 groups of 16). K/V dbuf in LDS.
__global__ __launch_bounds__(256, 2) void k_attn(const unsigned short* __restrict__ qb,
                                                 const unsigned short* __restrict__ kb,
                                                 const unsigned short* __restrict__ vb,
                                                 const unsigned long long* __restrict__ mb,
                                                 unsigned short* __restrict__ ob) {
  const int tid = threadIdx.x;
  const int w = tid >> 6, lane = tid & 63;
  const int c = lane & 15, g = lane >> 4;
  const int bid = blockIdx.x;
  const int q128 = bid & 7, h = (bid >> 3) & 15, n = bid >> 7;
  const int qlo = q128 * 128 + w * 32;

  __shared__ unsigned short Ks[2][64][64];   // [key][dpos], XOR-swizzled granules
  __shared__ unsigned short Vt[2][64][64];   // [d natural][keypos], XOR-swizzled
  __shared__ unsigned short Pl[4][32][64];   // per-wave [qrow][keypos], XOR-swizzled

  char* const Kb0 = (char*)&Ks[0][0][0];
  char* const Vb0 = (char*)&Vt[0][0][0];
  char* const Pc  = (char*)&Pl[w][0][0];

  const size_t nh = (size_t)(n * HEADS + h) * SEQ;
  const unsigned short* qp = qb + nh * HD;
  const char* kpB = (const char*)(kb + nh * HD);
  const unsigned short* vp = vb + nh * HD;
  const unsigned long long* mbq = mb + ((size_t)n * SEQ + qlo) * 16;

  // Q fragments, 2 row groups of 16
  bf16x8 qa[2][2];
  #pragma unroll
  for (int grp = 0; grp < 2; ++grp)
    #pragma unroll
    for (int ks = 0; ks < 2; ++ks)
      qa[grp][ks] = *(const bf16x8*)(qp + (size_t)(qlo + grp * 16 + c) * HD + ks * 32 + g * 8);

  f32x4 o[2][4] = {};
  float ls[2][4] = {{0.f,0.f,0.f,0.f},{0.f,0.f,0.f,0.f}};

  const int srow = tid >> 2;                       // V staging: key row
  const int sseg = tid & 3;                        // 16-dpos segment
  const int vpos = 4 * (srow & 15) + (srow >> 4);  // key permutation (P<->V consistent)
  uint4 vr0, vr1;

  // ---- prologue: tile 0 ----
  {
    const unsigned short* vsrc = vp + (size_t)srow * HD + sseg * 16;
    vr0 = *(const uint4*)vsrc; vr1 = *(const uint4*)(vsrc + 8);
    #pragma unroll
    for (int i = 0; i < 2; ++i) {
      const int off = i * 4096 + tid * 16;
      const int row = off >> 7, jslot = (off >> 4) & 7;
      gload_lds16(kpB + (size_t)row * 128 + ((jslot ^ (row & 7)) << 4), Kb0 + off);
    }
    const unsigned short* e0 = (const unsigned short*)&vr0;
    const unsigned short* e1 = (const unsigned short*)&vr1;
    #pragma unroll
    for (int j = 0; j < 8; ++j) {
      const int d = (j & 3) * 16 + sseg * 4 + (j >> 2);
      *(unsigned short*)(Vb0 + d * 128 + ((vpos * 2) ^ ((d & 7) << 4))) = e0[j];
    }
    #pragma unroll
    for (int j = 0; j < 8; ++j) {
      const int d = (j & 3) * 16 + sseg * 4 + 2 + (j >> 2);
      *(unsigned short*)(Vb0 + d * 128 + ((vpos * 2) ^ ((d & 7) << 4))) = e1[j];
    }
    __syncthreads();
  }

  for (int kt = 0; kt < 16; ++kt) {
    const int cur = kt & 1;
    char* const Kc = Kb0 + cur * 8192;
    char* const Vc = Vb0 + cur * 8192;
    char* const Ka = Kb0 + (cur ^ 1) * 8192;
    char* const Va = Vb0 + (cur ^ 1) * 8192;

    if (kt < 15) {
      const unsigned short* vsrc = vp + (size_t)((kt + 1) * 64 + srow) * HD + sseg * 16;
      vr0 = *(const uint4*)vsrc; vr1 = *(const uint4*)(vsrc + 8);
      #pragma unroll
      for (int i = 0; i < 2; ++i) {
        const int off = i * 4096 + tid * 16;
        const int row = off >> 7, jslot = (off >> 4) & 7;
        gload_lds16(kpB + (size_t)((kt + 1) * 64 + row) * 128 + ((jslot ^ (row & 7)) << 4),
                    Ka + off);
      }
    }

    // K fragments (shared by both row groups)
    bf16x8 kf[4][2];
    #pragma unroll
    for (int sub = 0; sub < 4; ++sub)
      #pragma unroll
      for (int ks = 0; ks < 2; ++ks)
        kf[sub][ks] = *(const bf16x8*)(Kc + (sub * 16 + c) * 128 + ((ks * 64 + g * 16) ^ ((c & 7) << 4)));

    #pragma unroll
    for (int grp = 0; grp < 2; ++grp) {
      f32x4 s[4];
      #pragma unroll
      for (int sub = 0; sub < 4; ++sub) {
        f32x4 acc = {};
        acc = __builtin_amdgcn_mfma_f32_16x16x32_bf16(qa[grp][0], kf[sub][0], acc, 0, 0, 0);
        acc = __builtin_amdgcn_mfma_f32_16x16x32_bf16(qa[grp][1], kf[sub][1], acc, 0, 0, 0);
        s[sub] = acc;
      }
      #pragma unroll
      for (int r = 0; r < 4; ++r) {
        const unsigned long long bits = mbq[(size_t)(grp * 16 + 4 * g + r) * 16 + kt];
        const unsigned long long sh = bits >> c;
        const float p0 = (sh & 1ull)         ? __expf(s[0][r]) : 0.f;
        const float p1 = ((sh >> 16) & 1ull) ? __expf(s[1][r]) : 0.f;
        const float p2 = ((sh >> 32) & 1ull) ? __expf(s[2][r]) : 0.f;
        const float p3 = ((sh >> 48) & 1ull) ? __expf(s[3][r]) : 0.f;
        ls[grp][r] += (p0 + p1) + (p2 + p3);
        ushort4 pk;
        pk.x = f2bf(p0); pk.y = f2bf(p1); pk.z = f2bf(p2); pk.w = f2bf(p3);
        const int prow = grp * 16 + 4 * g + r;
        *(ushort4*)(Pc + prow * 128 + ((8 * c) ^ ((prow & 7) << 4))) = pk;
      }
    }

    // PV: V fragments shared by both row groups
    bf16x8 vf[4][2];
    #pragma unroll
    for (int db = 0; db < 4; ++db)
      #pragma unroll
      for (int ks = 0; ks < 2; ++ks)
        vf[db][ks] = *(const bf16x8*)(Vc + (db * 16 + c) * 128 + ((ks * 64 + g * 16) ^ ((c & 7) << 4)));
    #pragma unroll
    for (int grp = 0; grp < 2; ++grp) {
      #pragma unroll
      for (int ks = 0; ks < 2; ++ks) {
        const bf16x8 pa = *(const bf16x8*)(Pc + (grp * 16 + c) * 128 + ((ks * 64 + g * 16) ^ ((c & 7) << 4)));
        #pragma unroll
        for (int db = 0; db < 4; ++db)
          o[grp][db] = __builtin_amdgcn_mfma_f32_16x16x32_bf16(pa, vf[db][ks], o[grp][db], 0, 0, 0);
      }
    }

    if (kt < 15) {
      const unsigned short* e0 = (const unsigned short*)&vr0;
      const unsigned short* e1 = (const unsigned short*)&vr1;
      #pragma unroll
      for (int j = 0; j < 8; ++j) {
        const int d = (j & 3) * 16 + sseg * 4 + (j >> 2);
        *(unsigned short*)(Va + d * 128 + ((vpos * 2) ^ ((d & 7) << 4))) = e0[j];
      }
      #pragma unroll
      for (int j = 0; j < 8; ++j) {
        const int d = (j & 3) * 16 + sseg * 4 + 2 + (j >> 2);
        *(unsigned short*)(Va + d * 128 + ((vpos * 2) ^ ((d & 7) << 4))) = e1[j];
      }
    }
    __syncthreads();
  }

  // epilogue: row-sum reduce (16-lane groups), normalize, packed store (E permuted)
  #pragma unroll
  for (int grp = 0; grp < 2; ++grp)
    #pragma unroll
    for (int r = 0; r < 4; ++r) {
      float l = ls[grp][r];
      l += __shfl_xor(l, 1); l += __shfl_xor(l, 2);
      l += __shfl_xor(l, 4); l += __shfl_xor(l, 8);
      const float inv = 1.0f / l;
      ushort4 pk;
      pk.x = f2bf(o[grp][0][r] * inv);
      pk.y = f2bf(o[grp][1][r] * inv);
      pk.z = f2bf(o[grp][2][r] * inv);
      pk.w = f2bf(o[grp][3][r] * inv);
      *(ushort4*)(ob + ((size_t)n * SEQ + qlo + grp * 16 + 4 * g + r) * EMB + h * 64 + 4 * c) = pk;
    }
}

// ---------------- out-proj GEMM: C[4096,1024] = A[4096,1024pi] * B[1024,1024pi]^T + bo ----------------
// 64x128 tile, BK=64, 512 blocks (2/CU), 4 waves each 64x32.
__global__ __launch_bounds__(256) void k_gemm(const unsigned short* __restrict__ A,
                                              const unsigned short* __restrict__ B,
                                              const float* __restrict__ bo,
                                              float* __restrict__ C) {
  const int tid = threadIdx.x;
  const int w = tid >> 6, lane = tid & 63;
  const int c = lane & 15, g = lane >> 4;
  const int bm = blockIdx.x & 63, bn = blockIdx.x >> 6;
  const int m0 = bm * 64, n0 = bn * 128;

  __shared__ unsigned short As[64][64];
  __shared__ unsigned short Bs[128][64];

  f32x4 acc[4][2] = {};

  for (int kt = 0; kt < 16; ++kt) {
    __syncthreads();
    #pragma unroll
    for (int i = 0; i < 2; ++i) {
      const int off = i * 4096 + tid * 16;
      const int row = off >> 7, colb = off & 127;
      gload_lds16((const char*)A + ((size_t)(m0 + row) * 1024 + kt * 64) * 2 + colb,
                  (char*)&As[0][0] + off);
    }
    #pragma unroll
    for (int i = 0; i < 4; ++i) {
      const int off = i * 4096 + tid * 16;
      const int row = off >> 7, colb = off & 127;
      gload_lds16((const char*)B + ((size_t)(n0 + row) * 1024 + kt * 64) * 2 + colb,
                  (char*)&Bs[0][0] + off);
    }
    __syncthreads();
    #pragma unroll
    for (int ks = 0; ks < 2; ++ks) {
      bf16x8 af[4], bf_[2];
      #pragma unroll
      for (int i = 0; i < 4; ++i)
        af[i] = *(const bf16x8*)&As[i * 16 + c][ks * 32 + g * 8];
      #pragma unroll
      for (int j = 0; j < 2; ++j)
        bf_[j] = *(const bf16x8*)&Bs[w * 32 + j * 16 + c][ks * 32 + g * 8];
      #pragma unroll
      for (int i = 0; i < 4; ++i)
        #pragma unroll
        for (int j = 0; j < 2; ++j)
          acc[i][j] = __builtin_amdgcn_mfma_f32_16x16x32_bf16(af[i], bf_[j], acc[i][j], 0, 0, 0);
    }
  }

  #pragma unroll
  for (int j = 0; j < 2; ++j) {
    const int col = n0 + w * 32 + j * 16 + c;
    const float bv = bo[col];
    #pragma unroll
    for (int i = 0; i < 4; ++i) {
      const int rowb = m0 + i * 16 + 4 * g;
      #pragma unroll
      for (int r = 0; r < 4; ++r)
        C[(size_t)(rowb + r) * 1024 + col] = acc[i][j][r] + bv;
    }
  }
}

extern "C" void kernel_launch(void* const* d_in, const int* in_sizes, int n_in,
                              void* d_out, int out_size, void* d_ws, size_t ws_size,
                              hipStream_t stream) {
  const float* values = (const float*)d_in[0];
  const float* query  = (const float*)d_in[1];
  const float* key    = (const float*)d_in[2];
  const int*   mask   = (const int*)d_in[3];
  const float* Wv     = (const float*)d_in[4];
  const float* Wk     = (const float*)d_in[5];
  const float* Wq     = (const float*)d_in[6];
  const float* Wo     = (const float*)d_in[7];
  const float* bo     = (const float*)d_in[8];
  float* out = (float*)d_out;

  char* ws = (char*)d_ws;
  unsigned short* qb = (unsigned short*)(ws);                            // 8MB  [N][H][S][Dpi]
  unsigned short* kb = (unsigned short*)(ws + (size_t)8 * 1024 * 1024);  // 8MB
  unsigned short* vb = (unsigned short*)(ws + (size_t)16 * 1024 * 1024); // 8MB
  unsigned short* ob = (unsigned short*)(ws + (size_t)24 * 1024 * 1024); // 8MB  [N][S][Epi]
  unsigned long long* mb = (unsigned long long*)(ws + (size_t)32 * 1024 * 1024); // 512KB
  unsigned short* wob = (unsigned short*)(ws + (size_t)33 * 1024 * 1024);        // 2MB

  k_maskpack<<<16384, 256, 0, stream>>>(mask, mb);
  k_cvtwo<<<1024, 256, 0, stream>>>(Wo, wob);
  k_proj<<<3072, 256, 0, stream>>>(values, query, key, Wv, Wq, Wk, vb, qb, kb);
  k_attn<<<512, 256, 0, stream>>>(qb, kb, vb, mb, ob);
  k_gemm<<<512, 256, 0, stream>>>(ob, wob, bo, out);
}